// Round 5
// baseline (304.352 us; speedup 1.0000x reference)
//
#include <hip/hip_runtime.h>

// LightGCN encoder: out = (A·e0 + A²·e0 + A³·e0)/3, A = 600K-edge COO.
// R10 vs R9:
//  (a) scatter/conv UNFUSED (R6+R9 evidence: heterogeneous block-partition
//      fusion co-schedules badly on gfx950 — latency partition drags
//      streaming partition to ~2TB/s; separate ≈30µs vs fused 55µs).
//  (b) spmm gather: 8 lanes/row x 2 uint4/lane (two 128B-contiguous row
//      halves). 4-deep edge unroll -> 8 independent loads/lane, the MLP
//      config measured at 5.5TB/s in R8's fp32 test, without dup loads.
//  (c) keep: bf16 intermediates (bytes/edge floor), atomic-free scatter
//      via precomputed rank, NT final stores, hist alone (atomics).
constexpr int USER_NUM = 100000;
constexpr int ITEM_NUM = 50000;
constexpr int N_NODES  = USER_NUM + ITEM_NUM;
constexpr int EMB      = 128;
constexpr int N_EDGES  = 600000;
constexpr int SCAN_BS  = 1024;

constexpr int EBLOCKS    = (N_EDGES + 255) / 256;       // 2344
constexpr int CVT_N      = N_NODES * EMB / 8;           // 2.4M uint4 outputs
constexpr int CVT_BLOCKS = CVT_N / 256;                 // 9375 exact

typedef float vf4 __attribute__((ext_vector_type(4))); // native, for NT stores

__device__ __forceinline__ float bf2f(unsigned u16) {
    return __uint_as_float(u16 << 16);
}
__device__ __forceinline__ unsigned f2bf(float f) {   // RTNE
    unsigned u = __float_as_uint(f);
    u += 0x7fffu + ((u >> 16) & 1u);
    return u >> 16;
}
__device__ __forceinline__ void fmadd_bf8(float* s, float v, uint4 g) {
    s[0] += v * bf2f(g.x & 0xffffu);
    s[1] += v * bf2f(g.x >> 16);
    s[2] += v * bf2f(g.y & 0xffffu);
    s[3] += v * bf2f(g.y >> 16);
    s[4] += v * bf2f(g.z & 0xffffu);
    s[5] += v * bf2f(g.z >> 16);
    s[6] += v * bf2f(g.w & 0xffffu);
    s[7] += v * bf2f(g.w >> 16);
}

// ---------------- e0 fp32 -> packed bf16 (standalone, streaming) --------
__global__ __launch_bounds__(256) void conv_k(
        const float4* __restrict__ ue, const float4* __restrict__ ie,
        uint4* __restrict__ xb) {
    int i = blockIdx.x * 256 + threadIdx.x;     // < CVT_N exactly
    const int u4 = USER_NUM * EMB / 4;          // 3.2M float4s
    int f = 2 * i;
    float4 a, c;
    if (f < u4) { a = ue[f]; c = ue[f + 1]; }
    else        { a = ie[f - u4]; c = ie[f + 1 - u4]; }
    uint4 o;
    o.x = f2bf(a.x) | (f2bf(a.y) << 16);
    o.y = f2bf(a.z) | (f2bf(a.w) << 16);
    o.z = f2bf(c.x) | (f2bf(c.y) << 16);
    o.w = f2bf(c.z) | (f2bf(c.w) << 16);
    xb[i] = o;
}

// ---------------- CSR build ----------------
// histogram + per-edge rank in one pass (atomic; kept ALONE on purpose)
__global__ void hist_rank_k(const int* __restrict__ er, int* __restrict__ cnt,
                            int* __restrict__ rank) {
    int e = blockIdx.x * 256 + threadIdx.x;
    if (e < N_EDGES) rank[e] = atomicAdd(&cnt[er[e]], 1);
}

// fused scan: per-block LDS scan + atomic global base -> rowinfo (start,cnt).
__global__ __launch_bounds__(SCAN_BS) void scan_fused_k(
        const int* __restrict__ cnt, int* __restrict__ gcount,
        int2* __restrict__ rowinfo) {
    __shared__ int sh[SCAN_BS];
    __shared__ int sbase;
    int i = blockIdx.x * SCAN_BS + threadIdx.x;
    int v = (i < N_NODES) ? cnt[i] : 0;
    sh[threadIdx.x] = v;
    __syncthreads();
    for (int off = 1; off < SCAN_BS; off <<= 1) {
        int t = (threadIdx.x >= off) ? sh[threadIdx.x - off] : 0;
        __syncthreads();
        sh[threadIdx.x] += t;
        __syncthreads();
    }
    if (threadIdx.x == SCAN_BS - 1)
        sbase = atomicAdd(gcount, sh[SCAN_BS - 1]);
    __syncthreads();
    if (i < N_NODES)
        rowinfo[i] = make_int2(sbase + sh[threadIdx.x] - v, v);
}

// atomic-free scatter: position = rowstart + precomputed rank
__global__ void scatter_k(const int* __restrict__ er, const int* __restrict__ ec,
                          const float* __restrict__ ev, const int* __restrict__ rank,
                          const int2* __restrict__ rowinfo, int2* __restrict__ edges) {
    int e = blockIdx.x * 256 + threadIdx.x;
    if (e >= N_EDGES) return;
    int p = rowinfo[er[e]].x + rank[e];
    edges[p] = make_int2(ec[e], __float_as_int(ev[e]));
}

// ---------------- gather SpMM (bf16 x, fp32 accumulate) ----------------
// 8 lanes/row, 2 uint4/lane (row halves at uint4 idx lane and lane+8).
// 32 rows per 256-block, 8 rows per wave. 4-deep edge unroll -> 8
// independent 16B loads per lane in flight (the 5.5TB/s MLP config, R8).
// MODE 0/1: out = bf16 layer buffer.
// MODE 2:   s = A*e2; read e1 (b0) and e2 (x) linearly; acc = (e1+e2+s)/3 fp32.
template <int MODE>
__global__ __launch_bounds__(256) void spmm_gather_bf(
        const uint4* __restrict__ x, const int2* __restrict__ rowinfo,
        const int2* __restrict__ edges, uint4* __restrict__ out,
        const uint4* __restrict__ b0, float* __restrict__ acc) {
    int row  = blockIdx.x * 32 + (threadIdx.x >> 3);
    int lane = threadIdx.x & 7;
    if (row >= N_NODES) return;
    int2 ri = rowinfo[row];
    int e0 = ri.x, eend = ri.x + ri.y;
    float s[16];
    #pragma unroll
    for (int j = 0; j < 16; ++j) s[j] = 0.f;
    for (int base = e0; base < eend; base += 4) {
        int i1 = (base + 1 < eend) ? base + 1 : eend - 1;
        int i2 = (base + 2 < eend) ? base + 2 : eend - 1;
        int i3 = (base + 3 < eend) ? base + 3 : eend - 1;
        int2 p0 = edges[base], p1 = edges[i1], p2 = edges[i2], p3 = edges[i3];
        float v0 = __int_as_float(p0.y);
        float v1 = (base + 1 < eend) ? __int_as_float(p1.y) : 0.f;
        float v2 = (base + 2 < eend) ? __int_as_float(p2.y) : 0.f;
        float v3 = (base + 3 < eend) ? __int_as_float(p3.y) : 0.f;
        const uint4* r0 = x + (size_t)p0.x * 16 + lane;
        const uint4* r1 = x + (size_t)p1.x * 16 + lane;
        const uint4* r2 = x + (size_t)p2.x * 16 + lane;
        const uint4* r3 = x + (size_t)p3.x * 16 + lane;
        // 8 independent 16B loads in flight per lane
        uint4 a0 = r0[0], c0 = r0[8];
        uint4 a1 = r1[0], c1 = r1[8];
        uint4 a2 = r2[0], c2 = r2[8];
        uint4 a3 = r3[0], c3 = r3[8];
        fmadd_bf8(s,     v0, a0); fmadd_bf8(s + 8, v0, c0);
        fmadd_bf8(s,     v1, a1); fmadd_bf8(s + 8, v1, c1);
        fmadd_bf8(s,     v2, a2); fmadd_bf8(s + 8, v2, c2);
        fmadd_bf8(s,     v3, a3); fmadd_bf8(s + 8, v3, c3);
    }
    size_t o = (size_t)row * 16 + lane;
    if (MODE < 2) {
        uint4 w0, w1;
        w0.x = f2bf(s[0])  | (f2bf(s[1])  << 16);
        w0.y = f2bf(s[2])  | (f2bf(s[3])  << 16);
        w0.z = f2bf(s[4])  | (f2bf(s[5])  << 16);
        w0.w = f2bf(s[6])  | (f2bf(s[7])  << 16);
        w1.x = f2bf(s[8])  | (f2bf(s[9])  << 16);
        w1.y = f2bf(s[10]) | (f2bf(s[11]) << 16);
        w1.z = f2bf(s[12]) | (f2bf(s[13]) << 16);
        w1.w = f2bf(s[14]) | (f2bf(s[15]) << 16);
        out[o] = w0;
        out[o + 8] = w1;
    } else {
        uint4 a0 = b0[o];           // e1 half A, linear bf16
        uint4 a1 = b0[o + 8];       // e1 half B
        uint4 x0v = x[o];           // e2 half A (same buffer we gather)
        uint4 x1v = x[o + 8];       // e2 half B
        const float k = 1.0f / 3.0f;
        vf4 r0, r1, r2, r3;
        r0.x = (s[0]  + bf2f(a0.x & 0xffffu) + bf2f(x0v.x & 0xffffu)) * k;
        r0.y = (s[1]  + bf2f(a0.x >> 16)     + bf2f(x0v.x >> 16))     * k;
        r0.z = (s[2]  + bf2f(a0.y & 0xffffu) + bf2f(x0v.y & 0xffffu)) * k;
        r0.w = (s[3]  + bf2f(a0.y >> 16)     + bf2f(x0v.y >> 16))     * k;
        r1.x = (s[4]  + bf2f(a0.z & 0xffffu) + bf2f(x0v.z & 0xffffu)) * k;
        r1.y = (s[5]  + bf2f(a0.z >> 16)     + bf2f(x0v.z >> 16))     * k;
        r1.z = (s[6]  + bf2f(a0.w & 0xffffu) + bf2f(x0v.w & 0xffffu)) * k;
        r1.w = (s[7]  + bf2f(a0.w >> 16)     + bf2f(x0v.w >> 16))     * k;
        r2.x = (s[8]  + bf2f(a1.x & 0xffffu) + bf2f(x1v.x & 0xffffu)) * k;
        r2.y = (s[9]  + bf2f(a1.x >> 16)     + bf2f(x1v.x >> 16))     * k;
        r2.z = (s[10] + bf2f(a1.y & 0xffffu) + bf2f(x1v.y & 0xffffu)) * k;
        r2.w = (s[11] + bf2f(a1.y >> 16)     + bf2f(x1v.y >> 16))     * k;
        r3.x = (s[12] + bf2f(a1.z & 0xffffu) + bf2f(x1v.z & 0xffffu)) * k;
        r3.y = (s[13] + bf2f(a1.z >> 16)     + bf2f(x1v.z >> 16))     * k;
        r3.z = (s[14] + bf2f(a1.w & 0xffffu) + bf2f(x1v.w & 0xffffu)) * k;
        r3.w = (s[15] + bf2f(a1.w >> 16)     + bf2f(x1v.w >> 16))     * k;
        // half A = fp32 vf4 indices row*32 + lane*2 .. +1
        // half B = row*32 + 16 + lane*2 .. +1
        vf4* dstA = reinterpret_cast<vf4*>(acc) + (size_t)row * 32 + (size_t)lane * 2;
        vf4* dstB = dstA + 16;
        __builtin_nontemporal_store(r0, dstA);
        __builtin_nontemporal_store(r1, dstA + 1);
        __builtin_nontemporal_store(r2, dstB);
        __builtin_nontemporal_store(r3, dstB + 1);
    }
}

// ---------------- fallback (atomic path, used only if ws too small) ----
__global__ void spmm_first_at(const float* __restrict__ ue, const float* __restrict__ ie,
                              const float* __restrict__ ev, const int* __restrict__ er,
                              const int* __restrict__ ec, float* __restrict__ out) {
    int tid = blockIdx.x * blockDim.x + threadIdx.x;
    int edge = tid >> 5;
    if (edge >= N_EDGES) return;
    int lane = tid & 31;
    int row = er[edge]; int col = ec[edge]; float v = ev[edge];
    const float* x = (col < USER_NUM) ? (ue + (size_t)col * EMB)
                                      : (ie + (size_t)(col - USER_NUM) * EMB);
    float4 g = ((const float4*)x)[lane];
    float* o = out + (size_t)row * EMB + lane * 4;
    atomicAdd(o + 0, v * g.x); atomicAdd(o + 1, v * g.y);
    atomicAdd(o + 2, v * g.z); atomicAdd(o + 3, v * g.w);
}
__global__ void spmm_at(const float* __restrict__ x, const float* __restrict__ ev,
                        const int* __restrict__ er, const int* __restrict__ ec,
                        float* __restrict__ out) {
    int tid = blockIdx.x * blockDim.x + threadIdx.x;
    int edge = tid >> 5;
    if (edge >= N_EDGES) return;
    int lane = tid & 31;
    int row = er[edge]; int col = ec[edge]; float v = ev[edge];
    float4 g = ((const float4*)(x + (size_t)col * EMB))[lane];
    float* o = out + (size_t)row * EMB + lane * 4;
    atomicAdd(o + 0, v * g.x); atomicAdd(o + 1, v * g.y);
    atomicAdd(o + 2, v * g.z); atomicAdd(o + 3, v * g.w);
}
__global__ void acc_add(float* __restrict__ acc, const float* __restrict__ cur,
                        float scale, int n4) {
    int i = blockIdx.x * blockDim.x + threadIdx.x;
    if (i >= n4) return;
    float4 a = ((const float4*)acc)[i];
    float4 c = ((const float4*)cur)[i];
    a.x = (a.x + c.x) * scale; a.y = (a.y + c.y) * scale;
    a.z = (a.z + c.z) * scale; a.w = (a.w + c.w) * scale;
    ((float4*)acc)[i] = a;
}

extern "C" void kernel_launch(void* const* d_in, const int* in_sizes, int n_in,
                              void* d_out, int out_size, void* d_ws, size_t ws_size,
                              hipStream_t stream) {
    const float* ue = (const float*)d_in[0];
    const float* ie = (const float*)d_in[1];
    const float* ev = (const float*)d_in[2];
    const int*   er = (const int*)d_in[3];
    const int*   ec = (const int*)d_in[4];
    float* acc = (float*)d_out;

    size_t nnodes16 = (size_t)N_NODES * 16;           // uint4 per row = 16

    // main-path workspace (bf16 buffers)
    uint4* x0   = (uint4*)d_ws;                       // e0 bf16, 38.4 MB
    uint4* e1b  = x0 + nnodes16;                      // e1 bf16
    uint4* e2b  = e1b + nnodes16;                     // e2 bf16
    int*   cnt  = (int*)(e2b + nnodes16);             // N_NODES
    int*   gcount = cnt + N_NODES;                    // 1 (zeroed with cnt)
    int2*  rowinfo = (int2*)(gcount + 1);             // N_NODES (start,count)
    int*   rank = (int*)(rowinfo + N_NODES);          // N_EDGES
    int2*  edges = (int2*)(rank + N_EDGES);           // N_EDGES packed (c,v)
    size_t needed = (char*)(edges + N_EDGES) - (char*)d_ws;

    const int BLOCK = 256;
    const int nscan = (N_NODES + SCAN_BS - 1) / SCAN_BS;   // 147

    if (ws_size >= needed) {
        // CSR build — every kernel homogeneous; no heterogeneous fusion.
        (void)hipMemsetAsync(cnt, 0, ((size_t)N_NODES + 1) * sizeof(int), stream);
        hist_rank_k<<<EBLOCKS, BLOCK, 0, stream>>>(er, cnt, rank);
        scan_fused_k<<<nscan, SCAN_BS, 0, stream>>>(cnt, gcount, rowinfo);
        scatter_k<<<EBLOCKS, BLOCK, 0, stream>>>(er, ec, ev, rank, rowinfo, edges);
        conv_k<<<CVT_BLOCKS, BLOCK, 0, stream>>>(
            (const float4*)ue, (const float4*)ie, x0);

        // 3 gather layers (32 rows per block)
        const int gblocks = (N_NODES + 31) / 32;      // 4688
        spmm_gather_bf<0><<<gblocks, BLOCK, 0, stream>>>(
            x0, rowinfo, edges, e1b, nullptr, nullptr);
        spmm_gather_bf<1><<<gblocks, BLOCK, 0, stream>>>(
            e1b, rowinfo, edges, e2b, nullptr, nullptr);
        spmm_gather_bf<2><<<gblocks, BLOCK, 0, stream>>>(
            e2b, rowinfo, edges, nullptr, e1b, acc);
    } else {
        // fallback: atomic path (fp32 buffers at d_ws)
        size_t nfloats = (size_t)N_NODES * EMB;
        float* buf0 = (float*)d_ws;
        float* buf1 = buf0 + nfloats;
        const int spmm_blocks = (N_EDGES * 32) / BLOCK;
        const int n4 = (int)(nfloats / 4);
        const int add_blocks = (n4 + BLOCK - 1) / BLOCK;
        (void)hipMemsetAsync(acc, 0, nfloats * sizeof(float), stream);
        (void)hipMemsetAsync(buf0, 0, nfloats * sizeof(float), stream);
        spmm_first_at<<<spmm_blocks, BLOCK, 0, stream>>>(ue, ie, ev, er, ec, buf0);
        acc_add<<<add_blocks, BLOCK, 0, stream>>>(acc, buf0, 1.0f, n4);
        (void)hipMemsetAsync(buf1, 0, nfloats * sizeof(float), stream);
        spmm_at<<<spmm_blocks, BLOCK, 0, stream>>>(buf0, ev, er, ec, buf1);
        acc_add<<<add_blocks, BLOCK, 0, stream>>>(acc, buf1, 1.0f, n4);
        (void)hipMemsetAsync(buf0, 0, nfloats * sizeof(float), stream);
        spmm_at<<<spmm_blocks, BLOCK, 0, stream>>>(buf1, ev, er, ec, buf0);
        acc_add<<<add_blocks, BLOCK, 0, stream>>>(acc, buf0, 1.0f / 3.0f, n4);
    }
}